// Round 1
// baseline (455.594 us; speedup 1.0000x reference)
//
#include <hip/hip_runtime.h>
#include <hip/hip_bf16.h>

using bf16 = __hip_bfloat16;
typedef __attribute__((ext_vector_type(8))) short bf16x8;
typedef __attribute__((ext_vector_type(4))) float f32x4;

static constexpr int Bb = 4, Ss = 2048, Dd = 1024, Hh = 16, HD = 64;
static constexpr int TD = 3 * Dd;            // 3072
static constexpr int Mrows = Bb * Ss;        // 8192

__device__ __forceinline__ void gload_lds16(const void* g, void* l) {
    __builtin_amdgcn_global_load_lds(
        (const __attribute__((address_space(1))) void*)g,
        (__attribute__((address_space(3))) void*)l, 16, 0, 0);
}

// ---------------- cast fp32 -> bf16, 4 elems/thread ----------------
__global__ void cast_f32_bf16(const float* __restrict__ in, bf16* __restrict__ out, int n4) {
    int i = blockIdx.x * blockDim.x + threadIdx.x;
    if (i >= n4) return;
    float4 v = ((const float4*)in)[i];
    bf16 t0 = __float2bfloat16(v.x), t1 = __float2bfloat16(v.y);
    bf16 t2 = __float2bfloat16(v.z), t3 = __float2bfloat16(v.w);
    unsigned int lo = (unsigned int)(*(unsigned short*)&t0) | ((unsigned int)(*(unsigned short*)&t1) << 16);
    unsigned int hi = (unsigned int)(*(unsigned short*)&t2) | ((unsigned int)(*(unsigned short*)&t3) << 16);
    uint2 o; o.x = lo; o.y = hi;
    *(uint2*)(out + 4l * i) = o;
}

// ---------------- GEMM: C[m,n] = sum_k A[m,k] * Bt[n,k] ----------------
// 128x128 tile, BK=32, 256 threads (4 waves, 2x2), 16x16x32 bf16 MFMA.
template<bool OUT_BF16>
__global__ __launch_bounds__(256, 2) void gemm_bt(
    const bf16* __restrict__ A, const bf16* __restrict__ Bt,
    bf16* __restrict__ Cb, float* __restrict__ Cf, const float* __restrict__ bias,
    int M, int N, int K)
{
    __shared__ __align__(16) bf16 As[128 * 32];
    __shared__ __align__(16) bf16 Bs[128 * 32];
    const int tid = threadIdx.x;
    const int lane = tid & 63, wid = tid >> 6;
    const int lc = lane & 15, lg = lane >> 4;
    const int wr = wid >> 1, wc = wid & 1;
    const long tile_m = (long)blockIdx.y * 128;
    const long tile_n = (long)blockIdx.x * 128;

    const f32x4 fz = {0.f, 0.f, 0.f, 0.f};
    f32x4 acc[4][4];
#pragma unroll
    for (int i = 0; i < 4; ++i)
#pragma unroll
        for (int j = 0; j < 4; ++j) acc[i][j] = fz;

    for (int k0 = 0; k0 < K; k0 += 32) {
#pragma unroll
        for (int it = 0; it < 2; ++it) {
            int c = tid + it * 256;        // 0..511 chunk of 16B
            int row = c >> 2, seg = c & 3;
            gload_lds16(A  + (tile_m + row) * (long)K + k0 + seg * 8, (char*)As + c * 16);
            gload_lds16(Bt + (tile_n + row) * (long)K + k0 + seg * 8, (char*)Bs + c * 16);
        }
        __syncthreads();
        bf16x8 af[4], bfr[4];
#pragma unroll
        for (int i = 0; i < 4; ++i) {
            af[i]  = *(const bf16x8*)(As + (wr * 64 + i * 16 + lc) * 32 + lg * 8);
            bfr[i] = *(const bf16x8*)(Bs + (wc * 64 + i * 16 + lc) * 32 + lg * 8);
        }
#pragma unroll
        for (int i = 0; i < 4; ++i)
#pragma unroll
            for (int j = 0; j < 4; ++j)
                acc[i][j] = __builtin_amdgcn_mfma_f32_16x16x32_bf16(af[i], bfr[j], acc[i][j], 0, 0, 0);
        __syncthreads();
    }
    // epilogue: C/D layout row=(lane>>4)*4+r, col=lane&15
#pragma unroll
    for (int i = 0; i < 4; ++i)
#pragma unroll
        for (int j = 0; j < 4; ++j)
#pragma unroll
            for (int r = 0; r < 4; ++r) {
                long row = tile_m + wr * 64 + i * 16 + lg * 4 + r;
                long col = tile_n + wc * 64 + j * 16 + lc;
                float v = acc[i][j][r];
                if constexpr (OUT_BF16) Cb[row * N + col] = __float2bfloat16(v);
                else                    Cf[row * N + col] = v + bias[col];
            }
}

// ---------------- causal flash attention ----------------
// grid: (S/64, B*H). 256 threads = 4 waves; wave w handles q rows [qbase+16w, +16).
// K/V tiles of 64 keys staged in LDS (XOR-swizzled rows). 16x16x32 MFMA.
__global__ __launch_bounds__(256) void attn_fwd(const bf16* __restrict__ qkv, bf16* __restrict__ out) {
    const int qblk = blockIdx.x;          // 0..31
    const int bh = blockIdx.y;            // 0..63
    const int b = bh >> 4, h = bh & 15;
    const int tid = threadIdx.x;
    const int lane = tid & 63, wid = tid >> 6;
    const int lc = lane & 15, lg = lane >> 4;

    __shared__ __align__(16) bf16 Ks[64 * 64];
    __shared__ __align__(16) bf16 Vs[64 * 64];
    __shared__ __align__(16) bf16 Ps[4][16 * 72];   // per-wave P tile, padded rows (144B)

    const long rowbase = (long)b * Ss;
    const int qbase = qblk * 64;
    const int q_lo = qbase + wid * 16;

    // Q fragments (A-layout: row=lane&15, k=(lane>>4)*8+i), two 32-wide d slices
    const bf16* qptr = qkv + (rowbase + q_lo + lc) * (long)TD + h * HD + lg * 8;
    const bf16x8 qa0 = *(const bf16x8*)(qptr);
    const bf16x8 qa1 = *(const bf16x8*)(qptr + 32);

    const f32x4 fz = {0.f, 0.f, 0.f, 0.f};
    f32x4 acc[4]; // O tile: acc[t][r] -> q row lg*4+r, d col t*16+lc
#pragma unroll
    for (int t = 0; t < 4; ++t) acc[t] = fz;
    float mx[4], l[4];
#pragma unroll
    for (int r = 0; r < 4; ++r) { mx[r] = -INFINITY; l[r] = 0.f; }

    for (int kt = 0; kt <= qblk; ++kt) {
        // ---- stage K,V (64x64 bf16 each), swizzled: byte ^= (row&7)<<4 ----
#pragma unroll
        for (int it = 0; it < 2; ++it) {
            int c = tid + it * 256;            // 0..511
            int row = c >> 3, seg = c & 7;
            long g = (rowbase + kt * 64 + row) * (long)TD + h * HD + seg * 8;
            float4 kv = *(const float4*)(qkv + g + Dd);
            float4 vv = *(const float4*)(qkv + g + 2 * Dd);
            int boff = (row * 128 + seg * 16) ^ ((row & 7) << 4);
            *(float4*)((char*)Ks + boff) = kv;
            *(float4*)((char*)Vs + boff) = vv;
        }
        __syncthreads();

        // ---- QK^T: 4 key tiles of 16 ----
        f32x4 sc[4];
#pragma unroll
        for (int t = 0; t < 4; ++t) {
            int krow = t * 16 + lc;
            int u = krow * 128 + lg * 16;
            int sw = (krow & 7) << 4;
            bf16x8 kb0 = *(const bf16x8*)((const char*)Ks + (u ^ sw));
            bf16x8 kb1 = *(const bf16x8*)((const char*)Ks + ((u + 64) ^ sw));
            f32x4 z = fz;
            z = __builtin_amdgcn_mfma_f32_16x16x32_bf16(qa0, kb0, z, 0, 0, 0);
            z = __builtin_amdgcn_mfma_f32_16x16x32_bf16(qa1, kb1, z, 0, 0, 0);
            sc[t] = z;
        }

        // ---- scale + causal mask ----
        const bool diag = (kt == qblk);
        float s[4][4];
#pragma unroll
        for (int t = 0; t < 4; ++t)
#pragma unroll
            for (int r = 0; r < 4; ++r) {
                float v = sc[t][r] * 0.125f;
                if (diag) {
                    int qg = q_lo + lg * 4 + r;
                    int kg = qbase + t * 16 + lc;
                    if (kg > qg) v = -INFINITY;
                }
                s[t][r] = v;
            }

        // ---- online softmax ----
        float pm[4];
#pragma unroll
        for (int r = 0; r < 4; ++r) {
            pm[r] = fmaxf(fmaxf(s[0][r], s[1][r]), fmaxf(s[2][r], s[3][r]));
            pm[r] = fmaxf(pm[r], __shfl_xor(pm[r], 1));
            pm[r] = fmaxf(pm[r], __shfl_xor(pm[r], 2));
            pm[r] = fmaxf(pm[r], __shfl_xor(pm[r], 4));
            pm[r] = fmaxf(pm[r], __shfl_xor(pm[r], 8));
        }
        float sf[4];
#pragma unroll
        for (int r = 0; r < 4; ++r) {
            float mn = fmaxf(mx[r], pm[r]);
            sf[r] = __expf(mx[r] - mn);
            mx[r] = mn;
            l[r] *= sf[r];
        }
#pragma unroll
        for (int t = 0; t < 4; ++t)
#pragma unroll
            for (int r = 0; r < 4; ++r) acc[t][r] *= sf[r];

        float psum[4] = {0.f, 0.f, 0.f, 0.f};
#pragma unroll
        for (int t = 0; t < 4; ++t)
#pragma unroll
            for (int r = 0; r < 4; ++r) {
                float p = __expf(s[t][r] - mx[r]);
                psum[r] += p;
                Ps[wid][(lg * 4 + r) * 72 + t * 16 + lc] = __float2bfloat16(p);
            }
#pragma unroll
        for (int r = 0; r < 4; ++r) {
            psum[r] += __shfl_xor(psum[r], 1);
            psum[r] += __shfl_xor(psum[r], 2);
            psum[r] += __shfl_xor(psum[r], 4);
            psum[r] += __shfl_xor(psum[r], 8);
            l[r] += psum[r];
        }
        __syncthreads();   // P visible (and Ks reads done)

        // ---- PV: O += P * V ----
#pragma unroll
        for (int ks = 0; ks < 2; ++ks) {
            bf16x8 pa = *(const bf16x8*)(&Ps[wid][lc * 72 + ks * 32 + lg * 8]);
#pragma unroll
            for (int t = 0; t < 4; ++t) {
                bf16x8 vb;
#pragma unroll
                for (int i = 0; i < 8; ++i) {
                    int j = ks * 32 + lg * 8 + i;
                    int boff = (j * 128 + t * 32 + lc * 2) ^ ((j & 7) << 4);
                    vb[i] = *(const short*)((const char*)Vs + boff);
                }
                acc[t] = __builtin_amdgcn_mfma_f32_16x16x32_bf16(pa, vb, acc[t], 0, 0, 0);
            }
        }
        __syncthreads();   // Vs free for next stage
    }

    // ---- normalize + store bf16 [b*S+q][h*64+d] ----
#pragma unroll
    for (int r = 0; r < 4; ++r) {
        float inv = 1.f / l[r];
#pragma unroll
        for (int t = 0; t < 4; ++t) {
            long orow = rowbase + q_lo + lg * 4 + r;
            int ocol = h * HD + t * 16 + lc;
            out[orow * Dd + ocol] = __float2bfloat16(acc[t][r] * inv);
        }
    }
}

extern "C" void kernel_launch(void* const* d_in, const int* in_sizes, int n_in,
                              void* d_out, int out_size, void* d_ws, size_t ws_size,
                              hipStream_t stream) {
    const float* x    = (const float*)d_in[0];   // [4,2048,1024]
    const float* Wqkv = (const float*)d_in[1];   // [3072,1024]
    const float* Wo_w = (const float*)d_in[2];   // [1024,1024]
    const float* Wo_b = (const float*)d_in[3];   // [1024]
    float* out = (float*)d_out;

    const size_t MB = 1ull << 20;
    char* ws = (char*)d_ws;
    bf16* xb    = (bf16*)(ws);             // 16 MB  (reused as attn output later)
    bf16* wqkvb = (bf16*)(ws + 16 * MB);   // 6 MB
    bf16* wob   = (bf16*)(ws + 22 * MB);   // 2 MB
    bf16* qkv   = (bf16*)(ws + 24 * MB);   // 48 MB
    bf16* attnb = xb;                      // overlap: xb dead after GEMM1

    // casts
    cast_f32_bf16<<<8192, 256, 0, stream>>>(x, xb, Mrows * Dd / 4);
    cast_f32_bf16<<<3072, 256, 0, stream>>>(Wqkv, wqkvb, TD * Dd / 4);
    cast_f32_bf16<<<1024, 256, 0, stream>>>(Wo_w, wob, Dd * Dd / 4);

    // qkv = x @ Wqkv^T  -> bf16 [8192, 3072]
    gemm_bt<true><<<dim3(TD / 128, Mrows / 128), 256, 0, stream>>>(
        xb, wqkvb, qkv, nullptr, nullptr, Mrows, TD, Dd);

    // attention -> bf16 [8192, 1024]
    attn_fwd<<<dim3(Ss / 64, Bb * Hh), 256, 0, stream>>>(qkv, attnb);

    // out = attn @ Wo^T + b  -> fp32
    gemm_bt<false><<<dim3(Dd / 128, Mrows / 128), 256, 0, stream>>>(
        attnb, wob, nullptr, out, Wo_b, Mrows, Dd, Dd);
}

// Round 2
// 252.848 us; speedup vs baseline: 1.8019x; 1.8019x over previous
//
#include <hip/hip_runtime.h>
#include <hip/hip_bf16.h>

using bf16 = __hip_bfloat16;
typedef __attribute__((ext_vector_type(8))) short bf16x8;
typedef __attribute__((ext_vector_type(4))) short bf16x4;
typedef __attribute__((ext_vector_type(4))) float f32x4;

static constexpr int Bb = 4, Ss = 2048, Dd = 1024, Hh = 16, HD = 64;
static constexpr int TD = 3 * Dd;            // 3072
static constexpr int Mrows = Bb * Ss;        // 8192

#define MFMA16(a, b, c) __builtin_amdgcn_mfma_f32_16x16x32_bf16((a), (b), (c), 0, 0, 0)

__device__ __forceinline__ void gload_lds16(const void* g, void* l) {
    __builtin_amdgcn_global_load_lds(
        (const __attribute__((address_space(1))) void*)g,
        (__attribute__((address_space(3))) void*)l, 16, 0, 0);
}

__device__ __forceinline__ unsigned lds_addr(const void* p) {
    return (unsigned)(unsigned long long)(const __attribute__((address_space(3))) char*)p;
}

__device__ __forceinline__ unsigned pack2bf(float a, float b) {
    bf16 x = __float2bfloat16(a), y = __float2bfloat16(b);
    return (unsigned)(*(unsigned short*)&x) | ((unsigned)(*(unsigned short*)&y) << 16);
}

// ---------------- cast fp32 -> bf16, 4 elems/thread ----------------
__global__ void cast_f32_bf16(const float* __restrict__ in, bf16* __restrict__ out, int n4) {
    int i = blockIdx.x * blockDim.x + threadIdx.x;
    if (i >= n4) return;
    float4 v = ((const float4*)in)[i];
    bf16 t0 = __float2bfloat16(v.x), t1 = __float2bfloat16(v.y);
    bf16 t2 = __float2bfloat16(v.z), t3 = __float2bfloat16(v.w);
    unsigned int lo = (unsigned int)(*(unsigned short*)&t0) | ((unsigned int)(*(unsigned short*)&t1) << 16);
    unsigned int hi = (unsigned int)(*(unsigned short*)&t2) | ((unsigned int)(*(unsigned short*)&t3) << 16);
    uint2 o; o.x = lo; o.y = hi;
    *(uint2*)(out + 4l * i) = o;
}

// ---------------- GEMM: C[m,n] = sum_k A[m,k] * Bt[n,k] ----------------
template<bool OUT_BF16>
__global__ __launch_bounds__(256, 2) void gemm_bt(
    const bf16* __restrict__ A, const bf16* __restrict__ Bt,
    bf16* __restrict__ Cb, float* __restrict__ Cf, const float* __restrict__ bias,
    int M, int N, int K)
{
    __shared__ __align__(16) bf16 As[128 * 32];
    __shared__ __align__(16) bf16 Bs[128 * 32];
    const int tid = threadIdx.x;
    const int lane = tid & 63, wid = tid >> 6;
    const int lc = lane & 15, lg = lane >> 4;
    const int wr = wid >> 1, wc = wid & 1;
    const long tile_m = (long)blockIdx.y * 128;
    const long tile_n = (long)blockIdx.x * 128;

    const f32x4 fz = {0.f, 0.f, 0.f, 0.f};
    f32x4 acc[4][4];
#pragma unroll
    for (int i = 0; i < 4; ++i)
#pragma unroll
        for (int j = 0; j < 4; ++j) acc[i][j] = fz;

    for (int k0 = 0; k0 < K; k0 += 32) {
#pragma unroll
        for (int it = 0; it < 2; ++it) {
            int c = tid + it * 256;
            int row = c >> 2, seg = c & 3;
            gload_lds16(A  + (tile_m + row) * (long)K + k0 + seg * 8, (char*)As + c * 16);
            gload_lds16(Bt + (tile_n + row) * (long)K + k0 + seg * 8, (char*)Bs + c * 16);
        }
        __syncthreads();
        bf16x8 af[4], bfr[4];
#pragma unroll
        for (int i = 0; i < 4; ++i) {
            af[i]  = *(const bf16x8*)(As + (wr * 64 + i * 16 + lc) * 32 + lg * 8);
            bfr[i] = *(const bf16x8*)(Bs + (wc * 64 + i * 16 + lc) * 32 + lg * 8);
        }
#pragma unroll
        for (int i = 0; i < 4; ++i)
#pragma unroll
            for (int j = 0; j < 4; ++j)
                acc[i][j] = MFMA16(af[i], bfr[j], acc[i][j]);
        __syncthreads();
    }
#pragma unroll
    for (int i = 0; i < 4; ++i)
#pragma unroll
        for (int j = 0; j < 4; ++j)
#pragma unroll
            for (int r = 0; r < 4; ++r) {
                long row = tile_m + wr * 64 + i * 16 + lg * 4 + r;
                long col = tile_n + wc * 64 + j * 16 + lc;
                float v = acc[i][j][r];
                if constexpr (OUT_BF16) Cb[row * N + col] = __float2bfloat16(v);
                else                    Cf[row * N + col] = v + bias[col];
            }
}

// ---------------- causal flash attention v2 ----------------
// grid: (B*H, S/128). 256 threads = 4 waves; wave w owns q rows [qb*128+32w, +32).
// Swapped QK^T (S^T = K·Q^T) -> in-register softmax. V in subtiled LDS layout,
// read via ds_read_b64_tr_b16. K/V double-buffered, 1 barrier per 64-key tile.
__global__ __launch_bounds__(256) void attn_fwd2(const bf16* __restrict__ qkv,
                                                 bf16* __restrict__ out) {
    const int bh = blockIdx.x;
    const int b = bh >> 4, h = bh & 15;
    const int qb = blockIdx.y;                 // 0..15
    const int tid = threadIdx.x;
    const int lane = tid & 63, wid = tid >> 6;
    const int lc = lane & 15, lg = lane >> 4;
    const long rowbase = (long)b * Ss;
    const int q0 = qb * 128 + wid * 32;        // wave's first q row
    const int nt = 2 * qb + 2;                 // # of 64-key tiles

    __shared__ __align__(16) bf16 Ks[2][64 * 64];
    __shared__ __align__(16) bf16 Vs[2][64 * 64];

    // staging coords: chunk c covers K/V[row][sg*8 .. +7]
    const int r0 = tid >> 3;                   // rows 0..31 (chunk 2: +32)
    const int sg = tid & 7;
    const int kb0 = (r0 * 128 + sg * 16) ^ ((r0 & 7) << 4);
    const int kb1 = ((r0 + 32) * 128 + sg * 16) ^ (((r0 + 32) & 7) << 4);
    const int vb0 = ((r0 >> 2) * 256 + (sg >> 1) * 64 + (r0 & 3) * 16 + (sg & 1) * 8) * 2;
    const int vb1 = (((r0 + 32) >> 2) * 256 + (sg >> 1) * 64 + ((r0 + 32) & 3) * 16 + (sg & 1) * 8) * 2;
    const bf16* gbase = qkv + (rowbase + r0) * (long)TD + h * HD + sg * 8;

    // Q fragments: qa[j][ds] -> B-operand: b[i] = Q[q0+j*16+lc][ds*32+lg*8+i]
    bf16x8 qa[2][2];
#pragma unroll
    for (int j = 0; j < 2; ++j)
#pragma unroll
        for (int ds = 0; ds < 2; ++ds)
            qa[j][ds] = *(const bf16x8*)(qkv + (rowbase + q0 + j * 16 + lc) * (long)TD
                                         + h * HD + ds * 32 + lg * 8);

    const f32x4 fz = {0.f, 0.f, 0.f, 0.f};
    f32x4 acc[2][4];                            // acc[j][t]: O[q0+j*16+lg*4+r][t*16+lc]
#pragma unroll
    for (int j = 0; j < 2; ++j)
#pragma unroll
        for (int t = 0; t < 4; ++t) acc[j][t] = fz;
    float mr[2] = {-3.0e38f, -3.0e38f};         // running max of raw scores (per q=lc)
    float l[2]  = {0.f, 0.f};
    const float CL2 = 0.18033688f;              // 0.125 * log2(e)

    // ---- prologue: stage tile 0 ----
    {
        float4 k0 = *(const float4*)(gbase + Dd);
        float4 v0 = *(const float4*)(gbase + 2 * Dd);
        float4 k1 = *(const float4*)(gbase + 32l * TD + Dd);
        float4 v1 = *(const float4*)(gbase + 32l * TD + 2 * Dd);
        *(float4*)((char*)Ks[0] + kb0) = k0;
        *(float4*)((char*)Ks[0] + kb1) = k1;
        *(float4*)((char*)Vs[0] + vb0) = v0;
        *(float4*)((char*)Vs[0] + vb1) = v1;
    }
    __syncthreads();

    for (int kt = 0; kt < nt; ++kt) {
        const int cur = kt & 1;
        const bool pf = (kt + 1 < nt);
        float4 pfK0, pfK1, pfV0, pfV1;
        if (pf) {
            const bf16* g = gbase + (long)(kt + 1) * 64 * TD;
            pfK0 = *(const float4*)(g + Dd);
            pfV0 = *(const float4*)(g + 2 * Dd);
            pfK1 = *(const float4*)(g + 32l * TD + Dd);
            pfV1 = *(const float4*)(g + 32l * TD + 2 * Dd);
        }

        if (kt * 64 <= q0 + 31) {               // wave has unmasked work in this tile
            // ---- QK^T (swapped): sc[t][j] = S^T[k=kt*64+t*16+lg*4+r][q=q0+j*16+lc]
            const char* kbp = (const char*)Ks[cur];
            f32x4 sc[4][2];
#pragma unroll
            for (int t = 0; t < 4; ++t) {
                const int row = t * 16 + lc;
                const int sw = (row & 7) << 4;
                const int rb = row * 128 + lg * 16;
                bf16x8 ka0 = *(const bf16x8*)(kbp + (rb ^ sw));
                bf16x8 ka1 = *(const bf16x8*)(kbp + ((rb + 64) ^ sw));
                sc[t][0] = MFMA16(ka0, qa[0][0], fz);
                sc[t][0] = MFMA16(ka1, qa[0][1], sc[t][0]);
                sc[t][1] = MFMA16(ka0, qa[1][0], fz);
                sc[t][1] = MFMA16(ka1, qa[1][1], sc[t][1]);
            }

            // ---- mask + online softmax (in-register, per lane q=lc) ----
            unsigned pk[2][4][2];
            float sf[2];
#pragma unroll
            for (int j = 0; j < 2; ++j) {
                if (kt * 64 + 63 > q0 + j * 16) {
                    const int qj = q0 + j * 16 + lc;
#pragma unroll
                    for (int t = 0; t < 4; ++t)
#pragma unroll
                        for (int r = 0; r < 4; ++r) {
                            int kg = kt * 64 + t * 16 + lg * 4 + r;
                            if (kg > qj) sc[t][j][r] = -3.0e38f;
                        }
                }
                float mx = fmaxf(
                    fmaxf(fmaxf(fmaxf(sc[0][j][0], sc[0][j][1]), fmaxf(sc[0][j][2], sc[0][j][3])),
                          fmaxf(fmaxf(sc[1][j][0], sc[1][j][1]), fmaxf(sc[1][j][2], sc[1][j][3]))),
                    fmaxf(fmaxf(fmaxf(sc[2][j][0], sc[2][j][1]), fmaxf(sc[2][j][2], sc[2][j][3])),
                          fmaxf(fmaxf(sc[3][j][0], sc[3][j][1]), fmaxf(sc[3][j][2], sc[3][j][3]))));
                mx = fmaxf(mx, __shfl_xor(mx, 16));
                mx = fmaxf(mx, __shfl_xor(mx, 32));
                float mnew = fmaxf(mr[j], mx);
                sf[j] = exp2f((mr[j] - mnew) * CL2);
                mr[j] = mnew;
                const float mt = mnew * CL2;
                float sum = 0.f;
#pragma unroll
                for (int t = 0; t < 4; ++t) {
                    float e0 = exp2f(fmaf(sc[t][j][0], CL2, -mt));
                    float e1 = exp2f(fmaf(sc[t][j][1], CL2, -mt));
                    float e2 = exp2f(fmaf(sc[t][j][2], CL2, -mt));
                    float e3 = exp2f(fmaf(sc[t][j][3], CL2, -mt));
                    sum += (e0 + e1) + (e2 + e3);
                    pk[j][t][0] = pack2bf(e0, e1);
                    pk[j][t][1] = pack2bf(e2, e3);
                }
                sum += __shfl_xor(sum, 16);
                sum += __shfl_xor(sum, 32);
                l[j] = l[j] * sf[j] + sum;
            }
            // ---- rescale O (sf lives at lane q=lc; acc row q=lg*4+r) ----
#pragma unroll
            for (int j = 0; j < 2; ++j)
#pragma unroll
                for (int r = 0; r < 4; ++r) {
                    float s = __shfl(sf[j], lg * 4 + r);
#pragma unroll
                    for (int t = 0; t < 4; ++t) acc[j][t][r] *= s;
                }

            // ---- PV: O += P·V  (V via hardware transpose reads) ----
#pragma unroll
            for (int ks = 0; ks < 2; ++ks) {
                bf16x4 vlo[4], vhi[4];
                const unsigned vbase = lds_addr(Vs[cur])
                                     + (unsigned)(((ks * 8 + lg * 2) * 256) * 2 + lc * 8);
#pragma unroll
                for (int t = 0; t < 4; ++t) {
                    asm volatile("ds_read_b64_tr_b16 %0, %2\n\t"
                                 "ds_read_b64_tr_b16 %1, %2 offset:512"
                                 : "=v"(vlo[t]), "=v"(vhi[t])
                                 : "v"(vbase + (unsigned)(t * 128)) : "memory");
                }
                // A-fragment exchange: dest lane (lg,lc) needs P[q=lc][k=ks*32+lg*8+i]
                const int srcA = ((lg & 1) << 5) + lc;
                const bool hi2 = (lane & 32) != 0;
                bf16x8 pa[2];
#pragma unroll
                for (int j = 0; j < 2; ++j) {
                    unsigned uA0 = __shfl((int)pk[j][ks * 2][0],     srcA);
                    unsigned uB0 = __shfl((int)pk[j][ks * 2 + 1][0], srcA);
                    unsigned uA1 = __shfl((int)pk[j][ks * 2][1],     srcA);
                    unsigned uB1 = __shfl((int)pk[j][ks * 2 + 1][1], srcA);
                    unsigned uA2 = __shfl((int)pk[j][ks * 2][0],     srcA + 16);
                    unsigned uB2 = __shfl((int)pk[j][ks * 2 + 1][0], srcA + 16);
                    unsigned uA3 = __shfl((int)pk[j][ks * 2][1],     srcA + 16);
                    unsigned uB3 = __shfl((int)pk[j][ks * 2 + 1][1], srcA + 16);
                    union { unsigned u[4]; bf16x8 v; } A;
                    A.u[0] = hi2 ? uB0 : uA0;
                    A.u[1] = hi2 ? uB1 : uA1;
                    A.u[2] = hi2 ? uB2 : uA2;
                    A.u[3] = hi2 ? uB3 : uA3;
                    pa[j] = A.v;
                }
                asm volatile("s_waitcnt lgkmcnt(0)" ::: "memory");
                __builtin_amdgcn_sched_barrier(0);
#pragma unroll
                for (int t = 0; t < 4; ++t) {
                    bf16x8 vb = __builtin_shufflevector(vlo[t], vhi[t], 0, 1, 2, 3, 4, 5, 6, 7);
                    acc[0][t] = MFMA16(pa[0], vb, acc[0][t]);
                    acc[1][t] = MFMA16(pa[1], vb, acc[1][t]);
                }
            }
        }

        if (pf) {
            const int nx = cur ^ 1;
            *(float4*)((char*)Ks[nx] + kb0) = pfK0;
            *(float4*)((char*)Ks[nx] + kb1) = pfK1;
            *(float4*)((char*)Vs[nx] + vb0) = pfV0;
            *(float4*)((char*)Vs[nx] + vb1) = pfV1;
        }
        __syncthreads();
    }

    // ---- normalize + store ----
#pragma unroll
    for (int j = 0; j < 2; ++j) {
        float invl = 1.f / l[j];
#pragma unroll
        for (int r = 0; r < 4; ++r) {
            float ir = __shfl(invl, lg * 4 + r);
            long orow = rowbase + q0 + j * 16 + lg * 4 + r;
#pragma unroll
            for (int t = 0; t < 4; ++t)
                out[orow * Dd + h * HD + t * 16 + lc] = __float2bfloat16(acc[j][t][r] * ir);
        }
    }
}

extern "C" void kernel_launch(void* const* d_in, const int* in_sizes, int n_in,
                              void* d_out, int out_size, void* d_ws, size_t ws_size,
                              hipStream_t stream) {
    const float* x    = (const float*)d_in[0];
    const float* Wqkv = (const float*)d_in[1];
    const float* Wo_w = (const float*)d_in[2];
    const float* Wo_b = (const float*)d_in[3];
    float* out = (float*)d_out;

    const size_t MB = 1ull << 20;
    char* ws = (char*)d_ws;
    bf16* xb    = (bf16*)(ws);
    bf16* wqkvb = (bf16*)(ws + 16 * MB);
    bf16* wob   = (bf16*)(ws + 22 * MB);
    bf16* qkv   = (bf16*)(ws + 24 * MB);
    bf16* attnb = xb;

    cast_f32_bf16<<<8192, 256, 0, stream>>>(x, xb, Mrows * Dd / 4);
    cast_f32_bf16<<<3072, 256, 0, stream>>>(Wqkv, wqkvb, TD * Dd / 4);
    cast_f32_bf16<<<1024, 256, 0, stream>>>(Wo_w, wob, Dd * Dd / 4);

    gemm_bt<true><<<dim3(TD / 128, Mrows / 128), 256, 0, stream>>>(
        xb, wqkvb, qkv, nullptr, nullptr, Mrows, TD, Dd);

    attn_fwd2<<<dim3(Bb * Hh, Ss / 128), 256, 0, stream>>>(qkv, attnb);

    gemm_bt<false><<<dim3(Dd / 128, Mrows / 128), 256, 0, stream>>>(
        attnb, wob, nullptr, out, Wo_b, Mrows, Dd, Dd);
}

// Round 3
// 180.206 us; speedup vs baseline: 2.5282x; 1.4031x over previous
//
#include <hip/hip_runtime.h>
#include <hip/hip_bf16.h>

using bf16 = __hip_bfloat16;
typedef __attribute__((ext_vector_type(8))) short bf16x8;
typedef __attribute__((ext_vector_type(4))) short bf16x4;
typedef __attribute__((ext_vector_type(4))) float f32x4;
typedef __attribute__((ext_vector_type(16))) float f32x16;

static constexpr int Bb = 4, Ss = 2048, Dd = 1024, Hh = 16, HD = 64;
static constexpr int TD = 3 * Dd;            // 3072
static constexpr int Mrows = Bb * Ss;        // 8192

#define MFMA16(a, b, c) __builtin_amdgcn_mfma_f32_16x16x32_bf16((a), (b), (c), 0, 0, 0)
#define MFMA32(a, b, c) __builtin_amdgcn_mfma_f32_32x32x16_bf16((a), (b), (c), 0, 0, 0)

__device__ __forceinline__ void gload_lds16(const void* g, void* l) {
    __builtin_amdgcn_global_load_lds(
        (const __attribute__((address_space(1))) void*)g,
        (__attribute__((address_space(3))) void*)l, 16, 0, 0);
}

__device__ __forceinline__ unsigned lds_addr(const void* p) {
    return (unsigned)(unsigned long long)(const __attribute__((address_space(3))) char*)p;
}

__device__ __forceinline__ unsigned pack2bf(float a, float b) {
    bf16 x = __float2bfloat16(a), y = __float2bfloat16(b);
    return (unsigned)(*(unsigned short*)&x) | ((unsigned)(*(unsigned short*)&y) << 16);
}

// ---------------- cast fp32 -> bf16, 4 elems/thread ----------------
__global__ void cast_f32_bf16(const float* __restrict__ in, bf16* __restrict__ out, int n4) {
    int i = blockIdx.x * blockDim.x + threadIdx.x;
    if (i >= n4) return;
    float4 v = ((const float4*)in)[i];
    bf16 t0 = __float2bfloat16(v.x), t1 = __float2bfloat16(v.y);
    bf16 t2 = __float2bfloat16(v.z), t3 = __float2bfloat16(v.w);
    unsigned int lo = (unsigned int)(*(unsigned short*)&t0) | ((unsigned int)(*(unsigned short*)&t1) << 16);
    unsigned int hi = (unsigned int)(*(unsigned short*)&t2) | ((unsigned int)(*(unsigned short*)&t3) << 16);
    uint2 o; o.x = lo; o.y = hi;
    *(uint2*)(out + 4l * i) = o;
}

// ---------------- GEMM: C[m,n] = sum_k A[m,k] * Bt[n,k] ----------------
template<bool OUT_BF16>
__global__ __launch_bounds__(256, 2) void gemm_bt(
    const bf16* __restrict__ A, const bf16* __restrict__ Bt,
    bf16* __restrict__ Cb, float* __restrict__ Cf, const float* __restrict__ bias,
    int M, int N, int K)
{
    __shared__ __align__(16) bf16 As[128 * 32];
    __shared__ __align__(16) bf16 Bs[128 * 32];
    const int tid = threadIdx.x;
    const int lane = tid & 63, wid = tid >> 6;
    const int lc = lane & 15, lg = lane >> 4;
    const int wr = wid >> 1, wc = wid & 1;
    const long tile_m = (long)blockIdx.y * 128;
    const long tile_n = (long)blockIdx.x * 128;

    const f32x4 fz = {0.f, 0.f, 0.f, 0.f};
    f32x4 acc[4][4];
#pragma unroll
    for (int i = 0; i < 4; ++i)
#pragma unroll
        for (int j = 0; j < 4; ++j) acc[i][j] = fz;

    for (int k0 = 0; k0 < K; k0 += 32) {
#pragma unroll
        for (int it = 0; it < 2; ++it) {
            int c = tid + it * 256;
            int row = c >> 2, seg = c & 3;
            gload_lds16(A  + (tile_m + row) * (long)K + k0 + seg * 8, (char*)As + c * 16);
            gload_lds16(Bt + (tile_n + row) * (long)K + k0 + seg * 8, (char*)Bs + c * 16);
        }
        __syncthreads();
        bf16x8 af[4], bfr[4];
#pragma unroll
        for (int i = 0; i < 4; ++i) {
            af[i]  = *(const bf16x8*)(As + (wr * 64 + i * 16 + lc) * 32 + lg * 8);
            bfr[i] = *(const bf16x8*)(Bs + (wc * 64 + i * 16 + lc) * 32 + lg * 8);
        }
#pragma unroll
        for (int i = 0; i < 4; ++i)
#pragma unroll
            for (int j = 0; j < 4; ++j)
                acc[i][j] = MFMA16(af[i], bfr[j], acc[i][j]);
        __syncthreads();
    }
#pragma unroll
    for (int i = 0; i < 4; ++i)
#pragma unroll
        for (int j = 0; j < 4; ++j)
#pragma unroll
            for (int r = 0; r < 4; ++r) {
                long row = tile_m + wr * 64 + i * 16 + lg * 4 + r;
                long col = tile_n + wc * 64 + j * 16 + lc;
                float v = acc[i][j][r];
                if constexpr (OUT_BF16) Cb[row * N + col] = __float2bfloat16(v);
                else                    Cf[row * N + col] = v + bias[col];
            }
}

// ---------------- causal flash attention v3 (32x32 MFMA, paired strips) ----
// grid: (8 pairs, B*H). 256 threads = 4 waves. Block handles q-strips p and
// 15-p (128 rows each); wave w owns rows [strip*128+32w, +32) of each strip.
// Swapped QK^T via mfma_32x32x16 -> q is lane-local (lane&31), k reg-local.
// P exchange to PV A-fragment: 16 cvt_pk + 8 v_permlane32_swap_b32.
// V in [k/4][d/16][4][16] subtiles, read via ds_read_b64_tr_b16.
// Defer-max (THR=8, log2 domain) skips O-rescale on most tiles.
__global__ __launch_bounds__(256, 2) void attn_fwd3(const bf16* __restrict__ qkv,
                                                    bf16* __restrict__ out) {
    const int p  = blockIdx.x;                 // 0..7
    const int bh = blockIdx.y;                 // 0..63
    const int b = bh >> 4, h = bh & 15;
    const int tid = threadIdx.x;
    const int lane = tid & 63, wid = tid >> 6;
    const int ln31 = lane & 31, hi = lane >> 5;
    const int ch = (lane >> 4) & 1, c16 = lane & 15;
    const long rowbase = (long)b * Ss;
    const int sA = p, sB = 15 - p;
    const int q0A = sA * 128 + wid * 32;
    const int q0B = sB * 128 + wid * 32;
    const int nt = 2 * sB + 2;
    const float CL2 = 0.18033688f;             // 0.125 * log2(e)

    __shared__ __align__(16) bf16 Ks[2][64 * 64];
    __shared__ __align__(16) bf16 Vs[2][64 * 64];

    // staging coords: thread writes K/V rows r0, r0+32, 8 bf16 at col sg*8
    const int r0 = tid >> 3;
    const int sg = tid & 7;
    const int kb0 = (r0 * 128 + sg * 16) ^ ((r0 & 7) << 4);
    const int kb1 = ((r0 + 32) * 128 + sg * 16) ^ (((r0 + 32) & 7) << 4);
    const int vb0 = ((r0 >> 2) * 256 + (sg >> 1) * 64 + (r0 & 3) * 16 + (sg & 1) * 8) * 2;
    const int vb1 = (((r0 + 32) >> 2) * 256 + (sg >> 1) * 64 + ((r0 + 32) & 3) * 16 + (sg & 1) * 8) * 2;
    const bf16* gbase = qkv + (rowbase + r0) * (long)TD + h * HD + sg * 8;

    // Q fragments (B-operand of 32x32x16): qa[dk][i] = Q[q0+ln31][dk*16+hi*8+i]
    bf16x8 qaA[4], qaB[4];
#pragma unroll
    for (int dk = 0; dk < 4; ++dk) {
        qaA[dk] = *(const bf16x8*)(qkv + (rowbase + q0A + ln31) * (long)TD + h * HD + dk * 16 + hi * 8);
        qaB[dk] = *(const bf16x8*)(qkv + (rowbase + q0B + ln31) * (long)TD + h * HD + dk * 16 + hi * 8);
    }

    f32x16 accA[2], accB[2];                   // acc[dt]: O[q=crow(r,hi)][dt*32+ln31]
#pragma unroll
    for (int dt = 0; dt < 2; ++dt) { accA[dt] = (f32x16)0.0f; accB[dt] = (f32x16)0.0f; }
    float m2A = -3.0e38f, m2B = -3.0e38f;      // running max, log2 units
    float lA = 0.f, lB = 0.f;

    // per-tile compute for one strip
    auto TILE = [&](int kt, int q0x, f32x16* acc, const bf16x8* qa,
                    float& m2, float& lsum, const char* kbp, const char* vbp) {
        // ---- QK^T swapped: sc[st][r] = S^T[k=st*32+crow(r,hi)][q=ln31] ----
        f32x16 sc[2];
#pragma unroll
        for (int st = 0; st < 2; ++st) {
            f32x16 z = (f32x16)0.0f;
            const int row = st * 32 + ln31;
            const int sw = (row & 7) << 4;
#pragma unroll
            for (int dk = 0; dk < 4; ++dk) {
                bf16x8 ka = *(const bf16x8*)(kbp + ((row * 128 + dk * 32 + hi * 16) ^ sw));
                z = MFMA32(ka, qa[dk], z);
            }
            sc[st] = z;
        }
        // ---- causal mask (diag tiles only) ----
        if (kt * 64 + 63 > q0x) {
            const int qg = q0x + ln31;
            const int kb = kt * 64 + 4 * hi;
#pragma unroll
            for (int st = 0; st < 2; ++st)
#pragma unroll
                for (int r = 0; r < 16; ++r) {
                    int kg = kb + st * 32 + (r & 3) + 8 * (r >> 2);
                    if (kg > qg) sc[st][r] = -3.0e38f;
                }
        }
        // ---- row max (in-lane 31 + cross-half) ----
        float mx = sc[0][0];
#pragma unroll
        for (int r = 1; r < 16; ++r) mx = fmaxf(mx, sc[0][r]);
#pragma unroll
        for (int r = 0; r < 16; ++r) mx = fmaxf(mx, sc[1][r]);
        mx = fmaxf(mx, __shfl_xor(mx, 32));
        float pmax2 = mx * CL2;
        // ---- defer-max: rescale only when max grew past THR=8 (rare) ----
        if (__ballot(pmax2 > m2 + 8.0f)) {
            float mnew = fmaxf(m2, pmax2);
            float sf = __builtin_amdgcn_exp2f(m2 - mnew);
            m2 = mnew;
            lsum *= sf;
#pragma unroll
            for (int r = 0; r < 16; ++r) {
                float sfr = __shfl(sf, (r & 3) + 8 * (r >> 2) + 4 * hi);
                acc[0][r] *= sfr;
                acc[1][r] *= sfr;
            }
        }
        // ---- issue all 16 V tr-reads early (latency hides under exp/pack) ----
        bf16x4 vl[4][2], vh[4][2];
        const unsigned vbase = lds_addr(vbp) + hi * 1024 + ch * 128 + c16 * 8;
#pragma unroll
        for (int ksg = 0; ksg < 4; ++ksg)
#pragma unroll
            for (int dt = 0; dt < 2; ++dt) {
                asm volatile("ds_read_b64_tr_b16 %0, %2\n\t"
                             "ds_read_b64_tr_b16 %1, %2 offset:512"
                             : "=v"(vl[ksg][dt]), "=v"(vh[ksg][dt])
                             : "v"(vbase + (unsigned)(ksg * 2048 + dt * 256)) : "memory");
            }
        // ---- exp + row-sum + pack ----
        const float mt = m2;
        float sum = 0.f;
        unsigned w[2][8];
#pragma unroll
        for (int st = 0; st < 2; ++st)
#pragma unroll
            for (int n = 0; n < 8; ++n) {
                float e0 = __builtin_amdgcn_exp2f(fmaf(sc[st][2 * n],     CL2, -mt));
                float e1 = __builtin_amdgcn_exp2f(fmaf(sc[st][2 * n + 1], CL2, -mt));
                sum += e0 + e1;
                w[st][n] = pack2bf(e0, e1);
            }
        sum += __shfl_xor(sum, 32);
        lsum += sum;
        // ---- P exchange: pa[ksg] via 2 permlane32_swap each ----
        union { unsigned u[4]; bf16x8 v; } pa[4];
#pragma unroll
        for (int ksg = 0; ksg < 4; ++ksg) {
            const int st = ksg >> 1, kl = ksg & 1;
            unsigned x0 = w[st][4 * kl],     y0 = w[st][4 * kl + 2];
            unsigned x1 = w[st][4 * kl + 1], y1 = w[st][4 * kl + 3];
            asm volatile("v_permlane32_swap_b32 %0, %1" : "+v"(x0), "+v"(y0));
            asm volatile("v_permlane32_swap_b32 %0, %1" : "+v"(x1), "+v"(y1));
            pa[ksg].u[0] = x0; pa[ksg].u[1] = x1; pa[ksg].u[2] = y0; pa[ksg].u[3] = y1;
        }
        // ---- PV ----
        asm volatile("s_waitcnt lgkmcnt(0)" ::: "memory");
        __builtin_amdgcn_sched_barrier(0);
#pragma unroll
        for (int ksg = 0; ksg < 4; ++ksg)
#pragma unroll
            for (int dt = 0; dt < 2; ++dt) {
                bf16x8 vb = __builtin_shufflevector(vl[ksg][dt], vh[ksg][dt],
                                                    0, 1, 2, 3, 4, 5, 6, 7);
                acc[dt] = MFMA32(pa[ksg].v, vb, acc[dt]);
            }
    };

    // ---- prologue: stage tile 0 ----
    {
        float4 k0 = *(const float4*)(gbase + Dd);
        float4 v0 = *(const float4*)(gbase + 2 * Dd);
        float4 k1 = *(const float4*)(gbase + 32l * TD + Dd);
        float4 v1 = *(const float4*)(gbase + 32l * TD + 2 * Dd);
        *(float4*)((char*)Ks[0] + kb0) = k0;
        *(float4*)((char*)Ks[0] + kb1) = k1;
        *(float4*)((char*)Vs[0] + vb0) = v0;
        *(float4*)((char*)Vs[0] + vb1) = v1;
    }
    __syncthreads();

    for (int kt = 0; kt < nt; ++kt) {
        const int cur = kt & 1;
        const bool pf = (kt + 1 < nt);
        float4 pfK0, pfK1, pfV0, pfV1;
        if (pf) {
            const bf16* g = gbase + (long)(kt + 1) * 64 * TD;
            pfK0 = *(const float4*)(g + Dd);
            pfV0 = *(const float4*)(g + 2 * Dd);
            pfK1 = *(const float4*)(g + 32l * TD + Dd);
            pfV1 = *(const float4*)(g + 32l * TD + 2 * Dd);
        }

        if (kt * 64 <= q0B + 31)
            TILE(kt, q0B, accB, qaB, m2B, lB, (const char*)Ks[cur], (const char*)Vs[cur]);
        if (kt * 64 <= q0A + 31)
            TILE(kt, q0A, accA, qaA, m2A, lA, (const char*)Ks[cur], (const char*)Vs[cur]);

        if (pf) {
            const int nx = cur ^ 1;
            *(float4*)((char*)Ks[nx] + kb0) = pfK0;
            *(float4*)((char*)Ks[nx] + kb1) = pfK1;
            *(float4*)((char*)Vs[nx] + vb0) = pfV0;
            *(float4*)((char*)Vs[nx] + vb1) = pfV1;
        }
        __syncthreads();
    }

    // ---- normalize + store both strips ----
    auto EPI = [&](const f32x16* acc, float l, int q0x) {
        float invl = 1.f / l;
#pragma unroll
        for (int r = 0; r < 16; ++r) {
            float ir = __shfl(invl, (r & 3) + 8 * (r >> 2) + 4 * hi);
            long orow = rowbase + q0x + (r & 3) + 8 * (r >> 2) + 4 * hi;
#pragma unroll
            for (int dt = 0; dt < 2; ++dt)
                out[orow * Dd + h * HD + dt * 32 + ln31] = __float2bfloat16(acc[dt][r] * ir);
        }
    };
    EPI(accA, lA, q0A);
    EPI(accB, lB, q0B);
}

extern "C" void kernel_launch(void* const* d_in, const int* in_sizes, int n_in,
                              void* d_out, int out_size, void* d_ws, size_t ws_size,
                              hipStream_t stream) {
    const float* x    = (const float*)d_in[0];
    const float* Wqkv = (const float*)d_in[1];
    const float* Wo_w = (const float*)d_in[2];
    const float* Wo_b = (const float*)d_in[3];
    float* out = (float*)d_out;

    const size_t MB = 1ull << 20;
    char* ws = (char*)d_ws;
    bf16* xb    = (bf16*)(ws);
    bf16* wqkvb = (bf16*)(ws + 16 * MB);
    bf16* wob   = (bf16*)(ws + 22 * MB);
    bf16* qkv   = (bf16*)(ws + 24 * MB);
    bf16* attnb = xb;

    cast_f32_bf16<<<8192, 256, 0, stream>>>(x, xb, Mrows * Dd / 4);
    cast_f32_bf16<<<3072, 256, 0, stream>>>(Wqkv, wqkvb, TD * Dd / 4);
    cast_f32_bf16<<<1024, 256, 0, stream>>>(Wo_w, wob, Dd * Dd / 4);

    gemm_bt<true><<<dim3(TD / 128, Mrows / 128), 256, 0, stream>>>(
        xb, wqkvb, qkv, nullptr, nullptr, Mrows, TD, Dd);

    attn_fwd3<<<dim3(8, Bb * Hh), 256, 0, stream>>>(qkv, attnb);

    gemm_bt<false><<<dim3(Dd / 128, Mrows / 128), 256, 0, stream>>>(
        attnb, wob, nullptr, out, Wo_b, Mrows, Dd, Dd);
}